// Round 1
// baseline (867.868 us; speedup 1.0000x reference)
//
#include <hip/hip_runtime.h>
#include <hip/hip_bf16.h>

#define NNODES 100000
#define NEDGES 1000000
#define HID 128
#define OUTF 16
#define BM 64
#define BK 32

// ---------------- CSR build ----------------

__global__ void hist_kernel(const int* __restrict__ dst, int* __restrict__ counts, int E) {
    int i = blockIdx.x * blockDim.x + threadIdx.x;
    if (i < E) atomicAdd(&counts[dst[i]], 1);
}

// per-block exclusive scan of 256 counts; block total -> bsum
__global__ void scan1(const int* __restrict__ counts, int* __restrict__ offs,
                      int* __restrict__ bsum, int N) {
    __shared__ int tmp[256];
    int t = threadIdx.x;
    int i = blockIdx.x * 256 + t;
    int v = (i < N) ? counts[i] : 0;
    tmp[t] = v;
    __syncthreads();
    for (int d = 1; d < 256; d <<= 1) {
        int add = (t >= d) ? tmp[t - d] : 0;
        __syncthreads();
        tmp[t] += add;
        __syncthreads();
    }
    if (i < N) offs[i] = tmp[t] - v;           // local exclusive
    if (t == 255) bsum[blockIdx.x] = tmp[255]; // block total
}

// single-block exclusive scan of block sums (nb <= 512)
__global__ void scan2(int* __restrict__ bsum, int nb) {
    __shared__ int tmp[512];
    int t = threadIdx.x;
    int v = (t < nb) ? bsum[t] : 0;
    tmp[t] = v;
    __syncthreads();
    for (int d = 1; d < 512; d <<= 1) {
        int add = (t >= d) ? tmp[t - d] : 0;
        __syncthreads();
        tmp[t] += add;
        __syncthreads();
    }
    if (t < nb) bsum[t] = tmp[t] - v; // exclusive
}

// add block offsets; compute inv = 1/(deg+1); set offs[N]=E
__global__ void scan3(int* __restrict__ offs, const int* __restrict__ bsum,
                      const int* __restrict__ counts, float* __restrict__ inv,
                      int N, int E) {
    int i = blockIdx.x * 256 + threadIdx.x;
    if (i < N) {
        offs[i] += bsum[blockIdx.x];
        inv[i] = 1.0f / (float)(counts[i] + 1);
    }
    if (i == 0) offs[N] = E;
}

__global__ void fill_csr(const int* __restrict__ src, const int* __restrict__ dst,
                         const int* __restrict__ offs, int* __restrict__ cursor,
                         int* __restrict__ csr_src, int E) {
    int e = blockIdx.x * blockDim.x + threadIdx.x;
    if (e < E) {
        int d = dst[e];
        int p = atomicAdd(&cursor[d], 1);
        csr_src[offs[d] + p] = src[e];
    }
}

// ---------------- fp32 GEMM: Z[M x 128] = A[M x 128] @ W[128 x 128] ----------------

__global__ __launch_bounds__(256) void gemm128(const float* __restrict__ A,
                                               const float* __restrict__ W,
                                               float* __restrict__ Z, int M) {
    __shared__ float hT[BK][BM + 1]; // A chunk transposed [k][r], +1 pad
    __shared__ float Ws[BK][HID];    // W chunk [k][c]
    int t = threadIdx.x;
    int cg = t & 15, rg = t >> 4;
    int c0 = cg * 8, r0 = rg * 4;
    int row0 = blockIdx.x * BM;

    float acc[4][8];
#pragma unroll
    for (int i = 0; i < 4; i++)
#pragma unroll
        for (int j = 0; j < 8; j++) acc[i][j] = 0.f;

    for (int k0 = 0; k0 < HID; k0 += BK) {
        // load W chunk: 32x128 floats, float4-coalesced
#pragma unroll
        for (int p = 0; p < 4; p++) {
            int idx = (t + p * 256) * 4; // 0..4092
            int kk = idx >> 7, cc = idx & 127;
            *(float4*)&Ws[kk][cc] = *(const float4*)&W[(size_t)(k0 + kk) * HID + cc];
        }
        // load A chunk transposed: 64 rows x 32 k
#pragma unroll
        for (int p = 0; p < 2; p++) {
            int idx = (t + p * 256) * 4; // 0..2044
            int rr = idx >> 5, kk = idx & 31;
            float4 v = make_float4(0.f, 0.f, 0.f, 0.f);
            if (row0 + rr < M)
                v = *(const float4*)&A[(size_t)(row0 + rr) * HID + k0 + kk];
            hT[kk + 0][rr] = v.x;
            hT[kk + 1][rr] = v.y;
            hT[kk + 2][rr] = v.z;
            hT[kk + 3][rr] = v.w;
        }
        __syncthreads();
#pragma unroll
        for (int kk = 0; kk < BK; kk++) {
            float a0 = hT[kk][r0 + 0];
            float a1 = hT[kk][r0 + 1];
            float a2 = hT[kk][r0 + 2];
            float a3 = hT[kk][r0 + 3];
            float4 w0 = *(float4*)&Ws[kk][c0];
            float4 w1 = *(float4*)&Ws[kk][c0 + 4];
            float w[8] = {w0.x, w0.y, w0.z, w0.w, w1.x, w1.y, w1.z, w1.w};
#pragma unroll
            for (int j = 0; j < 8; j++) {
                acc[0][j] += a0 * w[j];
                acc[1][j] += a1 * w[j];
                acc[2][j] += a2 * w[j];
                acc[3][j] += a3 * w[j];
            }
        }
        __syncthreads();
    }
#pragma unroll
    for (int i = 0; i < 4; i++) {
        int r = row0 + r0 + i;
        if (r < M) {
            *(float4*)&Z[(size_t)r * HID + c0] =
                make_float4(acc[i][0], acc[i][1], acc[i][2], acc[i][3]);
            *(float4*)&Z[(size_t)r * HID + c0 + 4] =
                make_float4(acc[i][4], acc[i][5], acc[i][6], acc[i][7]);
        }
    }
}

// ---------------- aggregate 128-wide: H[v] = relu(inv[v]*(Z[v]+sum Z[u]) + b) ----------------

__global__ __launch_bounds__(256) void agg128(const float* __restrict__ Z,
                                              const int* __restrict__ offs,
                                              const int* __restrict__ csr,
                                              const float* __restrict__ inv,
                                              const float* __restrict__ bias,
                                              float* __restrict__ H, int N, int do_relu) {
    int wave = (blockIdx.x * blockDim.x + threadIdx.x) >> 6;
    int lane = threadIdx.x & 63;
    if (wave >= N) return;
    int v = wave;
    float2 acc = *(const float2*)(Z + (size_t)v * HID + lane * 2);
    int beg = offs[v], end = offs[v + 1];
    for (int i = beg; i < end; ++i) {
        int u = csr[i];
        float2 tv = *(const float2*)(Z + (size_t)u * HID + lane * 2);
        acc.x += tv.x;
        acc.y += tv.y;
    }
    float s = inv[v];
    float2 b = *(const float2*)(bias + lane * 2);
    float rx = acc.x * s + b.x;
    float ry = acc.y * s + b.y;
    if (do_relu) {
        rx = fmaxf(rx, 0.f);
        ry = fmaxf(ry, 0.f);
    }
    *(float2*)(H + (size_t)v * HID + lane * 2) = make_float2(rx, ry);
}

// ---------------- layer 5: Z16 = H @ W5 (128 -> 16) ----------------

__global__ __launch_bounds__(256) void gemm16(const float* __restrict__ A,
                                              const float* __restrict__ W5,
                                              float* __restrict__ Z16, int M) {
    __shared__ float Ws[HID * OUTF]; // 8 KB
    int t = threadIdx.x;
    for (int i = t; i < HID * OUTF; i += 256) Ws[i] = W5[i];
    __syncthreads();
    int gid = blockIdx.x * 256 + t;
    int r = gid >> 4, c = gid & 15;
    if (r >= M) return;
    const float* a = A + (size_t)r * HID;
    float acc = 0.f;
#pragma unroll
    for (int k = 0; k < HID; k += 4) {
        float4 av = *(const float4*)&a[k];
        acc += av.x * Ws[(k + 0) * OUTF + c];
        acc += av.y * Ws[(k + 1) * OUTF + c];
        acc += av.z * Ws[(k + 2) * OUTF + c];
        acc += av.w * Ws[(k + 3) * OUTF + c];
    }
    Z16[(size_t)r * OUTF + c] = acc;
}

// ---------------- layer 5 aggregate + bias + log_softmax ----------------

__global__ __launch_bounds__(256) void agg16_lsm(const float* __restrict__ Z16,
                                                 const int* __restrict__ offs,
                                                 const int* __restrict__ csr,
                                                 const float* __restrict__ inv,
                                                 const float* __restrict__ b5,
                                                 float* __restrict__ out, int N) {
    int gid = blockIdx.x * 256 + threadIdx.x;
    int v = gid >> 4, c = gid & 15;
    if (v >= N) return;
    float acc = Z16[(size_t)v * OUTF + c];
    int beg = offs[v], end = offs[v + 1];
    for (int i = beg; i < end; ++i) {
        int u = csr[i];
        acc += Z16[(size_t)u * OUTF + c];
    }
    float val = acc * inv[v] + b5[c];
    // log-softmax across the 16 lanes of this node
    float m = val;
#pragma unroll
    for (int d = 1; d < 16; d <<= 1) m = fmaxf(m, __shfl_xor(m, d));
    float e = expf(val - m);
    float ssum = e;
#pragma unroll
    for (int d = 1; d < 16; d <<= 1) ssum += __shfl_xor(ssum, d);
    out[(size_t)v * OUTF + c] = val - m - logf(ssum);
}

// ---------------- launch ----------------

extern "C" void kernel_launch(void* const* d_in, const int* in_sizes, int n_in,
                              void* d_out, int out_size, void* d_ws, size_t ws_size,
                              hipStream_t stream) {
    const float* x   = (const float*)d_in[0];
    const int*   src = (const int*)d_in[1];
    const int*   dst = (const int*)d_in[2];
    const float* W1 = (const float*)d_in[3];
    const float* b1 = (const float*)d_in[4];
    const float* W2 = (const float*)d_in[5];
    const float* b2 = (const float*)d_in[6];
    const float* W3 = (const float*)d_in[7];
    const float* b3 = (const float*)d_in[8];
    const float* W4 = (const float*)d_in[9];
    const float* b4 = (const float*)d_in[10];
    const float* W5 = (const float*)d_in[11];
    const float* b5 = (const float*)d_in[12];

    char* ws = (char*)d_ws;
    size_t off = 0;
    auto alloc = [&](size_t bytes) {
        void* p = ws + off;
        off = (off + bytes + 255) & ~(size_t)255;
        return p;
    };
    float* zbuf   = (float*)alloc((size_t)NNODES * HID * 4);
    float* hbuf   = (float*)alloc((size_t)NNODES * HID * 4);
    int*   counts = (int*)alloc((size_t)NNODES * 4);       // also reused as cursor
    int*   offs   = (int*)alloc((size_t)(NNODES + 1) * 4);
    int*   bsum   = (int*)alloc(512 * 4);
    int*   csr    = (int*)alloc((size_t)NEDGES * 4);
    float* invd   = (float*)alloc((size_t)NNODES * 4);
    (void)ws_size; (void)in_sizes; (void)n_in; (void)out_size;

    const int N = NNODES, E = NEDGES;
    int nb = (N + 255) / 256; // 391

    // CSR build
    hipMemsetAsync(counts, 0, (size_t)N * 4, stream);
    hist_kernel<<<(E + 255) / 256, 256, 0, stream>>>(dst, counts, E);
    scan1<<<nb, 256, 0, stream>>>(counts, offs, bsum, N);
    scan2<<<1, 512, 0, stream>>>(bsum, nb);
    scan3<<<nb, 256, 0, stream>>>(offs, bsum, counts, invd, N, E);
    hipMemsetAsync(counts, 0, (size_t)N * 4, stream);
    fill_csr<<<(E + 255) / 256, 256, 0, stream>>>(src, dst, offs, counts, csr, E);

    int gemmGrid = (N + BM - 1) / BM;   // 1563
    int aggGrid  = (N + 3) / 4;         // 4 waves/block

    // layer 1
    gemm128<<<gemmGrid, 256, 0, stream>>>(x, W1, zbuf, N);
    agg128<<<aggGrid, 256, 0, stream>>>(zbuf, offs, csr, invd, b1, hbuf, N, 1);
    // layer 2
    gemm128<<<gemmGrid, 256, 0, stream>>>(hbuf, W2, zbuf, N);
    agg128<<<aggGrid, 256, 0, stream>>>(zbuf, offs, csr, invd, b2, hbuf, N, 1);
    // layer 3
    gemm128<<<gemmGrid, 256, 0, stream>>>(hbuf, W3, zbuf, N);
    agg128<<<aggGrid, 256, 0, stream>>>(zbuf, offs, csr, invd, b3, hbuf, N, 1);
    // layer 4
    gemm128<<<gemmGrid, 256, 0, stream>>>(hbuf, W4, zbuf, N);
    agg128<<<aggGrid, 256, 0, stream>>>(zbuf, offs, csr, invd, b4, hbuf, N, 1);
    // layer 5 (128 -> 16) + log_softmax
    gemm16<<<(N * OUTF + 255) / 256, 256, 0, stream>>>(hbuf, W5, zbuf, N);
    agg16_lsm<<<(N * OUTF + 255) / 256, 256, 0, stream>>>(zbuf, offs, csr, invd, b5,
                                                          (float*)d_out, N);
}

// Round 2
// 444.984 us; speedup vs baseline: 1.9503x; 1.9503x over previous
//
#include <hip/hip_runtime.h>
#include <hip/hip_bf16.h>

#define NNODES 100000
#define NEDGES 1000000
#define HID 128
#define OUTF 16

typedef __attribute__((ext_vector_type(8))) short short8;
typedef __attribute__((ext_vector_type(4))) float floatx4;
typedef unsigned int uint32;
typedef unsigned short ushort16;

__device__ __forceinline__ float blo(uint32 u) { return __uint_as_float(u << 16); }
__device__ __forceinline__ float bhi(uint32 u) { return __uint_as_float(u & 0xffff0000u); }
__device__ __forceinline__ ushort16 f2b(float f) {
    __hip_bfloat16 h = __float2bfloat16(f);
    return *reinterpret_cast<ushort16*>(&h);
}

// ---------------- CSR build ----------------

__global__ void hist_kernel(const int* __restrict__ dst, int* __restrict__ counts, int E) {
    int i = blockIdx.x * blockDim.x + threadIdx.x;
    if (i < E) atomicAdd(&counts[dst[i]], 1);
}

__global__ void scan1(const int* __restrict__ counts, int* __restrict__ offs,
                      int* __restrict__ bsum, int N) {
    __shared__ int tmp[256];
    int t = threadIdx.x;
    int i = blockIdx.x * 256 + t;
    int v = (i < N) ? counts[i] : 0;
    tmp[t] = v;
    __syncthreads();
    for (int d = 1; d < 256; d <<= 1) {
        int add = (t >= d) ? tmp[t - d] : 0;
        __syncthreads();
        tmp[t] += add;
        __syncthreads();
    }
    if (i < N) offs[i] = tmp[t] - v;
    if (t == 255) bsum[blockIdx.x] = tmp[255];
}

__global__ void scan2(int* __restrict__ bsum, int nb) {
    __shared__ int tmp[512];
    int t = threadIdx.x;
    int v = (t < nb) ? bsum[t] : 0;
    tmp[t] = v;
    __syncthreads();
    for (int d = 1; d < 512; d <<= 1) {
        int add = (t >= d) ? tmp[t - d] : 0;
        __syncthreads();
        tmp[t] += add;
        __syncthreads();
    }
    if (t < nb) bsum[t] = tmp[t] - v;
}

__global__ void scan3(int* __restrict__ offs, const int* __restrict__ bsum,
                      const int* __restrict__ counts, float* __restrict__ inv,
                      int N, int E) {
    int i = blockIdx.x * 256 + threadIdx.x;
    if (i < N) {
        offs[i] += bsum[blockIdx.x];
        inv[i] = 1.0f / (float)(counts[i] + 1);
    }
    if (i == 0) offs[N] = E;
}

__global__ void fill_csr(const int* __restrict__ src, const int* __restrict__ dst,
                         const int* __restrict__ offs, int* __restrict__ cursor,
                         int* __restrict__ csr_src, int E) {
    int e = blockIdx.x * blockDim.x + threadIdx.x;
    if (e < E) {
        int d = dst[e];
        int p = atomicAdd(&cursor[d], 1);
        csr_src[offs[d] + p] = src[e];
    }
}

// ---------------- weight pack: W[128x128] fp32 -> MFMA B-fragment order bf16 ----------------
// Wp layout: [nt(8)][ks(4)][lane(64)][i(8)] ; element = W[ks*32 + (lane>>4)*8 + i][nt*16 + (lane&15)]

__global__ void pack_w(const float* __restrict__ W, ushort16* __restrict__ Wp) {
    int b = blockIdx.x;      // 0..31 = nt*4 + ks
    int lane = threadIdx.x;  // 64
    int nt = b >> 2, ks = b & 3;
    int n = nt * 16 + (lane & 15);
    int kbase = ks * 32 + ((lane >> 4) << 3);
    ushort16 tmp[8];
#pragma unroll
    for (int i = 0; i < 8; i++) tmp[i] = f2b(W[(size_t)(kbase + i) * HID + n]);
    *(uint4*)&Wp[((size_t)b * 64 + lane) * 8] = *(uint4*)tmp;
}

// ---------------- MFMA GEMM: Z[M x 128](bf16) = A[M x 128] @ W ----------------
// 256 threads = 4 waves; wave w owns rows blk*64 + w*16 .. +15, all 128 output cols.

template <int AF32>
__global__ __launch_bounds__(256) void gemm_mfma(const void* __restrict__ Av,
                                                 const ushort16* __restrict__ Wp,
                                                 ushort16* __restrict__ Z, int M) {
    __shared__ __align__(16) ushort16 Wl[32 * 64 * 8];  // 32 KB
    int t = threadIdx.x;
    const uint4* wp4 = (const uint4*)Wp;
    uint4* wl4 = (uint4*)Wl;
#pragma unroll
    for (int p = 0; p < 8; p++) wl4[t + p * 256] = wp4[t + p * 256];
    __syncthreads();

    int wv = t >> 6, lane = t & 63;
    int row = blockIdx.x * 64 + wv * 16 + (lane & 15);
    int rowc = min(row, M - 1);
    int kb = (lane >> 4) << 3;

    short8 a[4];
    if (AF32) {
        const float* A = (const float*)Av;
#pragma unroll
        for (int ks = 0; ks < 4; ks++) {
            const float* p = A + (size_t)rowc * HID + ks * 32 + kb;
            floatx4 lo = *(const floatx4*)p;
            floatx4 hi = *(const floatx4*)(p + 4);
            union { short8 s; ushort16 u[8]; } cv;
            cv.u[0] = f2b(lo.x); cv.u[1] = f2b(lo.y); cv.u[2] = f2b(lo.z); cv.u[3] = f2b(lo.w);
            cv.u[4] = f2b(hi.x); cv.u[5] = f2b(hi.y); cv.u[6] = f2b(hi.z); cv.u[7] = f2b(hi.w);
            a[ks] = cv.s;
        }
    } else {
        const ushort16* A = (const ushort16*)Av;
#pragma unroll
        for (int ks = 0; ks < 4; ks++)
            a[ks] = *(const short8*)(A + (size_t)rowc * HID + ks * 32 + kb);
    }

    floatx4 acc[8];
#pragma unroll
    for (int nt = 0; nt < 8; nt++) acc[nt] = (floatx4){0.f, 0.f, 0.f, 0.f};

#pragma unroll
    for (int nt = 0; nt < 8; nt++) {
#pragma unroll
        for (int ks = 0; ks < 4; ks++) {
            short8 b = *(const short8*)&Wl[(size_t)(((nt << 2) | ks) * 64 + lane) * 8];
            acc[nt] = __builtin_amdgcn_mfma_f32_16x16x32_bf16(a[ks], b, acc[nt], 0, 0, 0);
        }
    }

    // C/D layout: col = lane&15, row_in_tile = (lane>>4)*4 + i   [m89]
    int orow = blockIdx.x * 64 + wv * 16 + ((lane >> 4) << 2);
    int col = lane & 15;
#pragma unroll
    for (int i = 0; i < 4; i++) {
        int r = orow + i;
        if (r < M) {
#pragma unroll
            for (int nt = 0; nt < 8; nt++)
                Z[(size_t)r * HID + nt * 16 + col] = f2b(acc[nt][i]);
        }
    }
}

// ---------------- aggregate (bf16 in / bf16 out, fp32 accum): one wave per node ----------------

__global__ __launch_bounds__(256) void agg_bf16(const uint32* __restrict__ Z,
                                                const int* __restrict__ offs,
                                                const int* __restrict__ csr,
                                                const float* __restrict__ inv,
                                                const float* __restrict__ bias,
                                                uint32* __restrict__ H, int N) {
    int v = (blockIdx.x * blockDim.x + threadIdx.x) >> 6;
    int lane = threadIdx.x & 63;
    if (v >= N) return;
    uint32 s = Z[(size_t)v * 64 + lane];
    float ax = blo(s), ay = bhi(s);
    int beg = offs[v], end = offs[v + 1];
    int i = beg;
    for (; i + 4 <= end; i += 4) {
        int u0 = csr[i], u1 = csr[i + 1], u2 = csr[i + 2], u3 = csr[i + 3];
        uint32 a0 = Z[(size_t)u0 * 64 + lane];
        uint32 a1 = Z[(size_t)u1 * 64 + lane];
        uint32 a2 = Z[(size_t)u2 * 64 + lane];
        uint32 a3 = Z[(size_t)u3 * 64 + lane];
        ax += blo(a0) + blo(a1) + blo(a2) + blo(a3);
        ay += bhi(a0) + bhi(a1) + bhi(a2) + bhi(a3);
    }
    for (; i < end; i++) {
        uint32 a0 = Z[(size_t)csr[i] * 64 + lane];
        ax += blo(a0);
        ay += bhi(a0);
    }
    float sc = inv[v];
    float2 b = *(const float2*)(bias + lane * 2);
    float rx = fmaxf(ax * sc + b.x, 0.f);
    float ry = fmaxf(ay * sc + b.y, 0.f);
    H[(size_t)v * 64 + lane] = (uint32)f2b(rx) | ((uint32)f2b(ry) << 16);
}

// ---------------- layer 5: Z16[M x 16] fp32 = H(bf16) @ W5 ----------------

__global__ __launch_bounds__(256) void gemm16(const ushort16* __restrict__ A,
                                              const float* __restrict__ W5,
                                              float* __restrict__ Z16, int M) {
    __shared__ float Ws[HID * OUTF];  // 8 KB
    int t = threadIdx.x;
    for (int i = t; i < HID * OUTF; i += 256) Ws[i] = W5[i];
    __syncthreads();
    int gid = blockIdx.x * 256 + t;
    int r = gid >> 4, c = gid & 15;
    if (r >= M) return;
    const uint32* a = (const uint32*)(A + (size_t)r * HID);
    float acc = 0.f;
#pragma unroll
    for (int k = 0; k < 64; k += 2) {
        uint32 u0 = a[k], u1 = a[k + 1];
        acc += blo(u0) * Ws[(2 * k + 0) * OUTF + c];
        acc += bhi(u0) * Ws[(2 * k + 1) * OUTF + c];
        acc += blo(u1) * Ws[(2 * k + 2) * OUTF + c];
        acc += bhi(u1) * Ws[(2 * k + 3) * OUTF + c];
    }
    Z16[(size_t)r * OUTF + c] = acc;
}

// ---------------- layer 5 aggregate + bias + log_softmax ----------------

__global__ __launch_bounds__(256) void agg16_lsm(const float* __restrict__ Z16,
                                                 const int* __restrict__ offs,
                                                 const int* __restrict__ csr,
                                                 const float* __restrict__ inv,
                                                 const float* __restrict__ b5,
                                                 float* __restrict__ out, int N) {
    int gid = blockIdx.x * 256 + threadIdx.x;
    int v = gid >> 4, c = gid & 15;
    if (v >= N) return;
    float acc = Z16[(size_t)v * OUTF + c];
    int beg = offs[v], end = offs[v + 1];
    int i = beg;
    for (; i + 2 <= end; i += 2) {
        int u0 = csr[i], u1 = csr[i + 1];
        acc += Z16[(size_t)u0 * OUTF + c] + Z16[(size_t)u1 * OUTF + c];
    }
    for (; i < end; i++) acc += Z16[(size_t)csr[i] * OUTF + c];
    float val = acc * inv[v] + b5[c];
    float m = val;
#pragma unroll
    for (int d = 1; d < 16; d <<= 1) m = fmaxf(m, __shfl_xor(m, d));
    float e = expf(val - m);
    float ssum = e;
#pragma unroll
    for (int d = 1; d < 16; d <<= 1) ssum += __shfl_xor(ssum, d);
    out[(size_t)v * OUTF + c] = val - m - logf(ssum);
}

// ---------------- launch ----------------

extern "C" void kernel_launch(void* const* d_in, const int* in_sizes, int n_in,
                              void* d_out, int out_size, void* d_ws, size_t ws_size,
                              hipStream_t stream) {
    const float* x   = (const float*)d_in[0];
    const int*   src = (const int*)d_in[1];
    const int*   dst = (const int*)d_in[2];
    const float* W1 = (const float*)d_in[3];
    const float* b1 = (const float*)d_in[4];
    const float* W2 = (const float*)d_in[5];
    const float* b2 = (const float*)d_in[6];
    const float* W3 = (const float*)d_in[7];
    const float* b3 = (const float*)d_in[8];
    const float* W4 = (const float*)d_in[9];
    const float* b4 = (const float*)d_in[10];
    const float* W5 = (const float*)d_in[11];
    const float* b5 = (const float*)d_in[12];

    char* ws = (char*)d_ws;
    size_t off = 0;
    auto alloc = [&](size_t bytes) {
        void* p = ws + off;
        off = (off + bytes + 255) & ~(size_t)255;
        return p;
    };
    ushort16* zb   = (ushort16*)alloc((size_t)NNODES * HID * 2);  // 25.6 MB bf16
    ushort16* hb   = (ushort16*)alloc((size_t)NNODES * HID * 2);  // 25.6 MB bf16
    float*    z16f = (float*)alloc((size_t)NNODES * OUTF * 4);    // 6.4 MB
    int*      counts = (int*)alloc((size_t)NNODES * 4);
    int*      offs   = (int*)alloc((size_t)(NNODES + 1) * 4);
    int*      bsum   = (int*)alloc(512 * 4);
    int*      csr    = (int*)alloc((size_t)NEDGES * 4);
    float*    invd   = (float*)alloc((size_t)NNODES * 4);
    ushort16* Wp1 = (ushort16*)alloc((size_t)HID * HID * 2);
    ushort16* Wp2 = (ushort16*)alloc((size_t)HID * HID * 2);
    ushort16* Wp3 = (ushort16*)alloc((size_t)HID * HID * 2);
    ushort16* Wp4 = (ushort16*)alloc((size_t)HID * HID * 2);
    (void)ws_size; (void)in_sizes; (void)n_in; (void)out_size;

    const int N = NNODES, E = NEDGES;
    int nb = (N + 255) / 256;

    // CSR build
    hipMemsetAsync(counts, 0, (size_t)N * 4, stream);
    hist_kernel<<<(E + 255) / 256, 256, 0, stream>>>(dst, counts, E);
    scan1<<<nb, 256, 0, stream>>>(counts, offs, bsum, N);
    scan2<<<1, 512, 0, stream>>>(bsum, nb);
    scan3<<<nb, 256, 0, stream>>>(offs, bsum, counts, invd, N, E);
    hipMemsetAsync(counts, 0, (size_t)N * 4, stream);
    fill_csr<<<(E + 255) / 256, 256, 0, stream>>>(src, dst, offs, counts, csr, E);

    // pack weights to MFMA fragment order
    pack_w<<<32, 64, 0, stream>>>(W1, Wp1);
    pack_w<<<32, 64, 0, stream>>>(W2, Wp2);
    pack_w<<<32, 64, 0, stream>>>(W3, Wp3);
    pack_w<<<32, 64, 0, stream>>>(W4, Wp4);

    int gemmGrid = (N + 63) / 64;  // 1563
    int aggGrid  = (N + 3) / 4;    // 25000

    gemm_mfma<1><<<gemmGrid, 256, 0, stream>>>((const void*)x, Wp1, zb, N);
    agg_bf16<<<aggGrid, 256, 0, stream>>>((const uint32*)zb, offs, csr, invd, b1, (uint32*)hb, N);

    gemm_mfma<0><<<gemmGrid, 256, 0, stream>>>((const void*)hb, Wp2, zb, N);
    agg_bf16<<<aggGrid, 256, 0, stream>>>((const uint32*)zb, offs, csr, invd, b2, (uint32*)hb, N);

    gemm_mfma<0><<<gemmGrid, 256, 0, stream>>>((const void*)hb, Wp3, zb, N);
    agg_bf16<<<aggGrid, 256, 0, stream>>>((const uint32*)zb, offs, csr, invd, b3, (uint32*)hb, N);

    gemm_mfma<0><<<gemmGrid, 256, 0, stream>>>((const void*)hb, Wp4, zb, N);
    agg_bf16<<<aggGrid, 256, 0, stream>>>((const uint32*)zb, offs, csr, invd, b4, (uint32*)hb, N);

    gemm16<<<(N * OUTF + 255) / 256, 256, 0, stream>>>(hb, W5, z16f, N);
    agg16_lsm<<<(N * OUTF + 255) / 256, 256, 0, stream>>>(z16f, offs, csr, invd, b5,
                                                          (float*)d_out, N);
}

// Round 3
// 411.009 us; speedup vs baseline: 2.1116x; 1.0827x over previous
//
#include <hip/hip_runtime.h>
#include <hip/hip_bf16.h>

#define NNODES 100000
#define NEDGES 1000000
#define HID 128
#define OUTF 16
#define NB 16       // dst-range buckets for CSR build
#define BCAP 81920  // per-bucket stage capacity (expected ~62500, sigma ~242)
#define KB 64       // blocks per bucket in fill2

typedef __attribute__((ext_vector_type(8))) short short8;
typedef __attribute__((ext_vector_type(4))) float floatx4;
typedef unsigned int uint32;
typedef unsigned short ushort16;

__device__ __forceinline__ float blo(uint32 u) { return __uint_as_float(u << 16); }
__device__ __forceinline__ float bhi(uint32 u) { return __uint_as_float(u & 0xffff0000u); }
__device__ __forceinline__ ushort16 f2b(float f) {
    __hip_bfloat16 h = __float2bfloat16(f);
    return *reinterpret_cast<ushort16*>(&h);
}

// ---------------- CSR build, bucketed ----------------

// Pass A: histogram counts + compact (src,dst) into NB dst-range buckets.
__global__ __launch_bounds__(256) void bucketize(const int* __restrict__ src,
                                                 const int* __restrict__ dst,
                                                 int* __restrict__ counts,
                                                 int* __restrict__ bcursor,
                                                 int2* __restrict__ stage, int E) {
    __shared__ int cnt[NB];
    __shared__ int base[NB];
    int t = threadIdx.x;
    int e = blockIdx.x * 256 + t;
    if (t < NB) cnt[t] = 0;
    __syncthreads();
    int s = 0, d = 0, b = 0, r = 0;
    bool valid = e < E;
    if (valid) {
        s = src[e];
        d = dst[e];
        atomicAdd(&counts[d], 1);
        b = (int)((unsigned)(d * NB) / (unsigned)NNODES);
        r = atomicAdd(&cnt[b], 1);
    }
    __syncthreads();
    if (t < NB) base[t] = atomicAdd(&bcursor[t], cnt[t]);
    __syncthreads();
    if (valid) {
        int pos = base[b] + r;
        if (pos < BCAP) stage[(size_t)b * BCAP + pos] = make_int2(s, d);
    }
}

// Pass B: scatter within one bucket's csr window; buckets pinned to XCDs via blockIdx%8.
__global__ __launch_bounds__(256) void fill2(const int2* __restrict__ stage,
                                             const int* __restrict__ bcursor,
                                             const int* __restrict__ offs,
                                             int* __restrict__ cursor,
                                             int* __restrict__ csr) {
    int blk = blockIdx.x;
    int b = (blk & 7) + 8 * ((blk >> 3) & 1);  // bucket, home XCD = b%8
    int slot = blk >> 4;                        // 0..KB-1
    int cntb = min(bcursor[b], BCAP);
    int per = (cntb + KB - 1) / KB;
    int s0 = slot * per;
    int s1 = min(s0 + per, cntb);
    const int2* st = stage + (size_t)b * BCAP;
    for (int i = s0 + threadIdx.x; i < s1; i += 256) {
        int2 sd = st[i];
        int p = atomicAdd(&cursor[sd.y], 1);
        csr[offs[sd.y] + p] = sd.x;
    }
}

__global__ void scan1(const int* __restrict__ counts, int* __restrict__ offs,
                      int* __restrict__ bsum, int N) {
    __shared__ int tmp[256];
    int t = threadIdx.x;
    int i = blockIdx.x * 256 + t;
    int v = (i < N) ? counts[i] : 0;
    tmp[t] = v;
    __syncthreads();
    for (int d = 1; d < 256; d <<= 1) {
        int add = (t >= d) ? tmp[t - d] : 0;
        __syncthreads();
        tmp[t] += add;
        __syncthreads();
    }
    if (i < N) offs[i] = tmp[t] - v;
    if (t == 255) bsum[blockIdx.x] = tmp[255];
}

__global__ void scan2(int* __restrict__ bsum, int nb) {
    __shared__ int tmp[512];
    int t = threadIdx.x;
    int v = (t < nb) ? bsum[t] : 0;
    tmp[t] = v;
    __syncthreads();
    for (int d = 1; d < 512; d <<= 1) {
        int add = (t >= d) ? tmp[t - d] : 0;
        __syncthreads();
        tmp[t] += add;
        __syncthreads();
    }
    if (t < nb) bsum[t] = tmp[t] - v;
}

__global__ void scan3(int* __restrict__ offs, const int* __restrict__ bsum,
                      const int* __restrict__ counts, float* __restrict__ inv,
                      int N, int E) {
    int i = blockIdx.x * 256 + threadIdx.x;
    if (i < N) {
        offs[i] += bsum[blockIdx.x];
        inv[i] = 1.0f / (float)(counts[i] + 1);
    }
    if (i == 0) offs[N] = E;
}

// ---------------- weight pack: W[128x128] fp32 -> MFMA B-fragment order bf16 ----------------
// Wp layout: [nt(8)][ks(4)][lane(64)][i(8)] ; element = W[ks*32 + (lane>>4)*8 + i][nt*16 + (lane&15)]

__global__ void pack_w(const float* __restrict__ W, ushort16* __restrict__ Wp) {
    int b = blockIdx.x;      // 0..31 = nt*4 + ks
    int lane = threadIdx.x;  // 64
    int nt = b >> 2, ks = b & 3;
    int n = nt * 16 + (lane & 15);
    int kbase = ks * 32 + ((lane >> 4) << 3);
    ushort16 tmp[8];
#pragma unroll
    for (int i = 0; i < 8; i++) tmp[i] = f2b(W[(size_t)(kbase + i) * HID + n]);
    *(uint4*)&Wp[((size_t)b * 64 + lane) * 8] = *(uint4*)tmp;
}

// ---------------- MFMA GEMM: Z[M x 128](bf16) = A[M x 128] @ W ----------------

template <int AF32>
__global__ __launch_bounds__(256) void gemm_mfma(const void* __restrict__ Av,
                                                 const ushort16* __restrict__ Wp,
                                                 ushort16* __restrict__ Z, int M) {
    __shared__ __align__(16) ushort16 Wl[32 * 64 * 8];  // 32 KB
    int t = threadIdx.x;
    const uint4* wp4 = (const uint4*)Wp;
    uint4* wl4 = (uint4*)Wl;
#pragma unroll
    for (int p = 0; p < 8; p++) wl4[t + p * 256] = wp4[t + p * 256];
    __syncthreads();

    int wv = t >> 6, lane = t & 63;
    int row = blockIdx.x * 64 + wv * 16 + (lane & 15);
    int rowc = min(row, M - 1);
    int kb = (lane >> 4) << 3;

    short8 a[4];
    if (AF32) {
        const float* A = (const float*)Av;
#pragma unroll
        for (int ks = 0; ks < 4; ks++) {
            const float* p = A + (size_t)rowc * HID + ks * 32 + kb;
            floatx4 lo = *(const floatx4*)p;
            floatx4 hi = *(const floatx4*)(p + 4);
            union { short8 s; ushort16 u[8]; } cv;
            cv.u[0] = f2b(lo.x); cv.u[1] = f2b(lo.y); cv.u[2] = f2b(lo.z); cv.u[3] = f2b(lo.w);
            cv.u[4] = f2b(hi.x); cv.u[5] = f2b(hi.y); cv.u[6] = f2b(hi.z); cv.u[7] = f2b(hi.w);
            a[ks] = cv.s;
        }
    } else {
        const ushort16* A = (const ushort16*)Av;
#pragma unroll
        for (int ks = 0; ks < 4; ks++)
            a[ks] = *(const short8*)(A + (size_t)rowc * HID + ks * 32 + kb);
    }

    floatx4 acc[8];
#pragma unroll
    for (int nt = 0; nt < 8; nt++) acc[nt] = (floatx4){0.f, 0.f, 0.f, 0.f};

#pragma unroll
    for (int nt = 0; nt < 8; nt++) {
#pragma unroll
        for (int ks = 0; ks < 4; ks++) {
            short8 b = *(const short8*)&Wl[(size_t)(((nt << 2) | ks) * 64 + lane) * 8];
            acc[nt] = __builtin_amdgcn_mfma_f32_16x16x32_bf16(a[ks], b, acc[nt], 0, 0, 0);
        }
    }

    int orow = blockIdx.x * 64 + wv * 16 + ((lane >> 4) << 2);
    int col = lane & 15;
#pragma unroll
    for (int i = 0; i < 4; i++) {
        int r = orow + i;
        if (r < M) {
#pragma unroll
            for (int nt = 0; nt < 8; nt++)
                Z[(size_t)r * HID + nt * 16 + col] = f2b(acc[nt][i]);
        }
    }
}

// ---------------- aggregate: one wave per node, indices prefetched to lane regs ----------------

__global__ __launch_bounds__(256) void agg_bf16(const uint32* __restrict__ Z,
                                                const int* __restrict__ offs,
                                                const int* __restrict__ csr,
                                                const float* __restrict__ inv,
                                                const float* __restrict__ bias,
                                                uint32* __restrict__ H, int N) {
    int v = (blockIdx.x * blockDim.x + threadIdx.x) >> 6;
    int lane = threadIdx.x & 63;
    if (v >= N) return;
    uint32 sv = Z[(size_t)v * 64 + lane];
    float ax = blo(sv), ay = bhi(sv);
    int beg = offs[v], cnt = offs[v + 1] - beg;
    for (int c0 = 0; c0 < cnt; c0 += 64) {
        int m = min(cnt - c0, 64);
        int idx = (lane < m) ? csr[beg + c0 + lane] : 0;
        int j = 0;
        for (; j + 8 <= m; j += 8) {
            uint32 a[8];
#pragma unroll
            for (int q = 0; q < 8; q++) {
                int u = __builtin_amdgcn_readlane(idx, j + q);
                a[q] = Z[(size_t)u * 64 + lane];
            }
#pragma unroll
            for (int q = 0; q < 8; q++) { ax += blo(a[q]); ay += bhi(a[q]); }
        }
        if (j + 4 <= m) {
            uint32 a[4];
#pragma unroll
            for (int q = 0; q < 4; q++) {
                int u = __builtin_amdgcn_readlane(idx, j + q);
                a[q] = Z[(size_t)u * 64 + lane];
            }
#pragma unroll
            for (int q = 0; q < 4; q++) { ax += blo(a[q]); ay += bhi(a[q]); }
            j += 4;
        }
        for (; j < m; ++j) {
            int u = __builtin_amdgcn_readlane(idx, j);
            uint32 a0 = Z[(size_t)u * 64 + lane];
            ax += blo(a0);
            ay += bhi(a0);
        }
    }
    float sc = inv[v];
    float2 b = *(const float2*)(bias + lane * 2);
    float rx = fmaxf(ax * sc + b.x, 0.f);
    float ry = fmaxf(ay * sc + b.y, 0.f);
    H[(size_t)v * 64 + lane] = (uint32)f2b(rx) | ((uint32)f2b(ry) << 16);
}

// ---------------- layer 5: Z16[M x 16] fp32 = H(bf16) @ W5 ----------------

__global__ __launch_bounds__(256) void gemm16(const ushort16* __restrict__ A,
                                              const float* __restrict__ W5,
                                              float* __restrict__ Z16, int M) {
    __shared__ float Ws[HID * OUTF];  // 8 KB
    int t = threadIdx.x;
    for (int i = t; i < HID * OUTF; i += 256) Ws[i] = W5[i];
    __syncthreads();
    int gid = blockIdx.x * 256 + t;
    int r = gid >> 4, c = gid & 15;
    if (r >= M) return;
    const uint32* a = (const uint32*)(A + (size_t)r * HID);
    float acc = 0.f;
#pragma unroll
    for (int k = 0; k < 64; k += 2) {
        uint32 u0 = a[k], u1 = a[k + 1];
        acc += blo(u0) * Ws[(2 * k + 0) * OUTF + c];
        acc += bhi(u0) * Ws[(2 * k + 1) * OUTF + c];
        acc += blo(u1) * Ws[(2 * k + 2) * OUTF + c];
        acc += bhi(u1) * Ws[(2 * k + 3) * OUTF + c];
    }
    Z16[(size_t)r * OUTF + c] = acc;
}

// ---------------- layer 5 aggregate + bias + log_softmax ----------------

__global__ __launch_bounds__(256) void agg16_lsm(const float* __restrict__ Z16,
                                                 const int* __restrict__ offs,
                                                 const int* __restrict__ csr,
                                                 const float* __restrict__ inv,
                                                 const float* __restrict__ b5,
                                                 float* __restrict__ out, int N) {
    int gid = blockIdx.x * 256 + threadIdx.x;
    int v = gid >> 4, c = gid & 15;
    if (v >= N) return;
    int beg = offs[v], cnt = offs[v + 1] - beg;
    float acc = Z16[(size_t)v * OUTF + c];
    for (int c0 = 0; c0 < cnt; c0 += 16) {
        int m = min(cnt - c0, 16);
        int idx = (c < m) ? csr[beg + c0 + c] : 0;
        int j = 0;
        for (; j + 4 <= m; j += 4) {
            int u0 = __shfl(idx, j, 16);
            int u1 = __shfl(idx, j + 1, 16);
            int u2 = __shfl(idx, j + 2, 16);
            int u3 = __shfl(idx, j + 3, 16);
            float a0 = Z16[(size_t)u0 * OUTF + c];
            float a1 = Z16[(size_t)u1 * OUTF + c];
            float a2 = Z16[(size_t)u2 * OUTF + c];
            float a3 = Z16[(size_t)u3 * OUTF + c];
            acc += a0 + a1 + a2 + a3;
        }
        for (; j < m; ++j) {
            int u = __shfl(idx, j, 16);
            acc += Z16[(size_t)u * OUTF + c];
        }
    }
    float val = acc * inv[v] + b5[c];
    float m = val;
#pragma unroll
    for (int d = 1; d < 16; d <<= 1) m = fmaxf(m, __shfl_xor(m, d));
    float e = expf(val - m);
    float ssum = e;
#pragma unroll
    for (int d = 1; d < 16; d <<= 1) ssum += __shfl_xor(ssum, d);
    out[(size_t)v * OUTF + c] = val - m - logf(ssum);
}

// ---------------- launch ----------------

extern "C" void kernel_launch(void* const* d_in, const int* in_sizes, int n_in,
                              void* d_out, int out_size, void* d_ws, size_t ws_size,
                              hipStream_t stream) {
    const float* x   = (const float*)d_in[0];
    const int*   src = (const int*)d_in[1];
    const int*   dst = (const int*)d_in[2];
    const float* W1 = (const float*)d_in[3];
    const float* b1 = (const float*)d_in[4];
    const float* W2 = (const float*)d_in[5];
    const float* b2 = (const float*)d_in[6];
    const float* W3 = (const float*)d_in[7];
    const float* b3 = (const float*)d_in[8];
    const float* W4 = (const float*)d_in[9];
    const float* b4 = (const float*)d_in[10];
    const float* W5 = (const float*)d_in[11];
    const float* b5 = (const float*)d_in[12];

    char* ws = (char*)d_ws;
    size_t off = 0;
    auto alloc = [&](size_t bytes) {
        void* p = ws + off;
        off = (off + bytes + 255) & ~(size_t)255;
        return p;
    };
    ushort16* zb   = (ushort16*)alloc((size_t)NNODES * HID * 2);
    ushort16* hb   = (ushort16*)alloc((size_t)NNODES * HID * 2);
    float*    z16f = (float*)alloc((size_t)NNODES * OUTF * 4);
    int*      counts = (int*)alloc((size_t)NNODES * 4);  // reused as cursor
    int*      offs   = (int*)alloc((size_t)(NNODES + 1) * 4);
    int*      bsum   = (int*)alloc(512 * 4);
    int*      csr    = (int*)alloc((size_t)NEDGES * 4);
    float*    invd   = (float*)alloc((size_t)NNODES * 4);
    int2*     stage  = (int2*)alloc((size_t)NB * BCAP * 8);
    int*      bcursor = (int*)alloc(NB * 4);
    ushort16* Wp1 = (ushort16*)alloc((size_t)HID * HID * 2);
    ushort16* Wp2 = (ushort16*)alloc((size_t)HID * HID * 2);
    ushort16* Wp3 = (ushort16*)alloc((size_t)HID * HID * 2);
    ushort16* Wp4 = (ushort16*)alloc((size_t)HID * HID * 2);
    (void)ws_size; (void)in_sizes; (void)n_in; (void)out_size;

    const int N = NNODES, E = NEDGES;
    int nb = (N + 255) / 256;

    // CSR build (bucketed)
    hipMemsetAsync(counts, 0, (size_t)N * 4, stream);
    hipMemsetAsync(bcursor, 0, NB * 4, stream);
    bucketize<<<(E + 255) / 256, 256, 0, stream>>>(src, dst, counts, bcursor, stage, E);
    scan1<<<nb, 256, 0, stream>>>(counts, offs, bsum, N);
    scan2<<<1, 512, 0, stream>>>(bsum, nb);
    scan3<<<nb, 256, 0, stream>>>(offs, bsum, counts, invd, N, E);
    hipMemsetAsync(counts, 0, (size_t)N * 4, stream);
    fill2<<<NB * KB, 256, 0, stream>>>(stage, bcursor, offs, counts, csr);

    // pack weights
    pack_w<<<32, 64, 0, stream>>>(W1, Wp1);
    pack_w<<<32, 64, 0, stream>>>(W2, Wp2);
    pack_w<<<32, 64, 0, stream>>>(W3, Wp3);
    pack_w<<<32, 64, 0, stream>>>(W4, Wp4);

    int gemmGrid = (N + 63) / 64;
    int aggGrid  = (N + 3) / 4;

    gemm_mfma<1><<<gemmGrid, 256, 0, stream>>>((const void*)x, Wp1, zb, N);
    agg_bf16<<<aggGrid, 256, 0, stream>>>((const uint32*)zb, offs, csr, invd, b1, (uint32*)hb, N);

    gemm_mfma<0><<<gemmGrid, 256, 0, stream>>>((const void*)hb, Wp2, zb, N);
    agg_bf16<<<aggGrid, 256, 0, stream>>>((const uint32*)zb, offs, csr, invd, b2, (uint32*)hb, N);

    gemm_mfma<0><<<gemmGrid, 256, 0, stream>>>((const void*)hb, Wp3, zb, N);
    agg_bf16<<<aggGrid, 256, 0, stream>>>((const uint32*)zb, offs, csr, invd, b3, (uint32*)hb, N);

    gemm_mfma<0><<<gemmGrid, 256, 0, stream>>>((const void*)hb, Wp4, zb, N);
    agg_bf16<<<aggGrid, 256, 0, stream>>>((const uint32*)zb, offs, csr, invd, b4, (uint32*)hb, N);

    gemm16<<<(N * OUTF + 255) / 256, 256, 0, stream>>>(hb, W5, z16f, N);
    agg16_lsm<<<(N * OUTF + 255) / 256, 256, 0, stream>>>(z16f, offs, csr, invd, b5,
                                                          (float*)d_out, N);
}